// Round 16
// baseline (141.406 us; speedup 1.0000x reference)
//
#include <hip/hip_runtime.h>
#include <stdint.h>

// MAB block: B=32, N=512, D=512, H=8, dh=64.  M = B*N = 16384.
#define SCALE_ 0.044194173824159216f
// scale * log2(e): folded into the q-projection so attention uses exp2 directly.
#define QSC_ (0.044194173824159216f * 1.4426950408889634f)

typedef __attribute__((ext_vector_type(8))) short bf16x8;
typedef __attribute__((ext_vector_type(4))) float f32x4;
typedef __attribute__((ext_vector_type(16))) float f32x16;
typedef __attribute__((ext_vector_type(2))) unsigned int uint2v;

__device__ __forceinline__ ushort f2b(float f) {
  union { float f; uint32_t u; } v; v.f = f;
  return (ushort)((v.u + 0x7fffu + ((v.u >> 16) & 1u)) >> 16);  // RNE
}
__device__ __forceinline__ uint32_t cvtpk(float lo, float hi) {
  uint32_t r; asm("v_cvt_pk_bf16_f32 %0, %1, %2" : "=v"(r) : "v"(lo), "v"(hi)); return r;
}
__device__ __forceinline__ float ex2(float x) {          // 2^x (v_exp_f32)
  float r; asm("v_exp_f32 %0, %1" : "=v"(r) : "v"(x)); return r;
}
__device__ __forceinline__ void gld16(void* lds, const void* g) {
  __builtin_amdgcn_global_load_lds(
      (const __attribute__((address_space(1))) uint32_t*)g,
      (__attribute__((address_space(3))) uint32_t*)lds, 16, 0, 0);
}

// ---------------- fp32 -> bf16 convert (weights only) ----------------
__global__ __launch_bounds__(256)
void k_cvtw(const float* __restrict__ w0, const float* __restrict__ w1,
            const float* __restrict__ w2, const float* __restrict__ w3,
            const float* __restrict__ w4, const float* __restrict__ w5,
            ushort* __restrict__ Wb)
{
  const int NW = 262144;
  int i = (blockIdx.x * 256 + threadIdx.x) * 4;
  int seg = i >> 18;
  int off = i & (NW - 1);
  const float* src;
  switch (seg) { case 0: src = w0; break; case 1: src = w1; break; case 2: src = w2; break;
                 case 3: src = w3; break; case 4: src = w4; break; default: src = w5; }
  float4 v = *(const float4*)(src + off);
  ushort4 o = make_ushort4(f2b(v.x), f2b(v.y), f2b(v.z), f2b(v.w));
  *(ushort4*)(Wb + (size_t)seg * NW + off) = o;
}

// ---------------- tail GEMM: C = A(bf16,[M,512]) @ Bw(bf16,[512,512])^T ----------------
// 256x128 tile, BK=64, 8 waves, triple-buffered, counted vmcnt(6), slot swizzle.
// EPI: 1 = Q + (acc+bias) -> f32 + bf16   2 = relu->bf16   3 = out += acc+bias
template<int EPI>
__device__ __forceinline__ void gemm_body(const ushort* __restrict__ A, const ushort* __restrict__ Bw,
                                          const float* __restrict__ bias, const float* __restrict__ extra,
                                          float* __restrict__ outf, ushort* __restrict__ outb,
                                          char* lds, int m0, int n0)
{
  const int t = threadIdx.x;
  const int w = t >> 6, lane = t & 63;
  const int wm = w >> 1, wn = w & 1;
  const int rA = lane & 15, g = lane >> 4;

  const ushort* srcA[4]; int ldsA[4];
#pragma unroll
  for (int j = 0; j < 4; j++) {
    int L = (t + j*512) * 16;
    int U = L ^ (((L >> 7) & 7) << 4);
    srcA[j] = A + (size_t)(m0 + (U >> 7))*512 + ((U & 127) >> 1);
    ldsA[j] = L;
  }
  const ushort* srcB[2]; int ldsB[2];
#pragma unroll
  for (int j = 0; j < 2; j++) {
    int L = (t + j*512) * 16;
    int U = L ^ (((L >> 7) & 7) << 4);
    srcB[j] = Bw + (size_t)(n0 + (U >> 7))*512 + ((U & 127) >> 1);
    ldsB[j] = 32768 + L;
  }

#define STAGE_T(ti) do { char* bb_ = lds + ((ti) % 3) * 49152; \
    _Pragma("unroll") \
    for (int j = 0; j < 4; j++) gld16(bb_ + ldsA[j], srcA[j] + (ti)*64); \
    _Pragma("unroll") \
    for (int j = 0; j < 2; j++) gld16(bb_ + ldsB[j], srcB[j] + (ti)*64); } while (0)

  STAGE_T(0); STAGE_T(1);

  f32x4 acc[4][4] = {};
  for (int i = 0; i < 8; i++) {
    if (i < 7) asm volatile("s_waitcnt vmcnt(6)" ::: "memory");
    else       asm volatile("s_waitcnt vmcnt(0)" ::: "memory");
    __builtin_amdgcn_s_barrier();
    __builtin_amdgcn_sched_barrier(0);
    const char* bufc = lds + (i % 3) * 49152;

    bf16x8 afA[4], bfA[4], afB[4], bfB[4];
#pragma unroll
    for (int m = 0; m < 4; m++) {
      int row = wm*64 + m*16 + rA;
      afA[m] = *(const bf16x8*)(bufc + ((row*128 + g*16) ^ ((row & 7) << 4)));
      afB[m] = *(const bf16x8*)(bufc + ((row*128 + 64 + g*16) ^ ((row & 7) << 4)));
    }
#pragma unroll
    for (int n = 0; n < 4; n++) {
      int row = wn*64 + n*16 + rA;
      bfA[n] = *(const bf16x8*)(bufc + 32768 + ((row*128 + g*16) ^ ((row & 7) << 4)));
      bfB[n] = *(const bf16x8*)(bufc + 32768 + ((row*128 + 64 + g*16) ^ ((row & 7) << 4)));
    }
    if (i < 6) STAGE_T(i + 2);
    __builtin_amdgcn_sched_barrier(0);
    __builtin_amdgcn_s_setprio(1);
#pragma unroll
    for (int m = 0; m < 4; m++)
#pragma unroll
      for (int n = 0; n < 4; n++)
        acc[m][n] = __builtin_amdgcn_mfma_f32_16x16x32_bf16(afA[m], bfA[n], acc[m][n], 0, 0, 0);
#pragma unroll
    for (int m = 0; m < 4; m++)
#pragma unroll
      for (int n = 0; n < 4; n++)
        acc[m][n] = __builtin_amdgcn_mfma_f32_16x16x32_bf16(afB[m], bfB[n], acc[m][n], 0, 0, 0);
    __builtin_amdgcn_s_setprio(0);
  }
#undef STAGE_T

#pragma unroll
  for (int m = 0; m < 4; m++)
#pragma unroll
    for (int n = 0; n < 4; n++) {
      int col = n0 + wn*64 + n*16 + rA;
      float bb = bias[col];
#pragma unroll
      for (int r = 0; r < 4; r++) {
        int row = m0 + wm*64 + m*16 + g*4 + r;
        size_t idx = (size_t)row*512 + col;
        float v = acc[m][n][r] + bb;
        if (EPI == 1)      { float o = extra[idx] + v; outf[idx] = o; outb[idx] = f2b(o); }
        else if (EPI == 2) outb[idx] = f2b(v > 0.f ? v : 0.f);
        else               outf[idx] += v;
      }
    }
}

template<int EPI>
__global__ __launch_bounds__(512, 2)
void k_gemm(const ushort* __restrict__ A, const ushort* __restrict__ Bw,
            const float* __restrict__ bias, const float* __restrict__ extra,
            float* __restrict__ outf, ushort* __restrict__ outb)
{
  __shared__ __align__(16) char lds[3*49152];   // 144 KB
  gemm_body<EPI>(A, Bw, bias, extra, outf, outb, lds, blockIdx.x*256, blockIdx.y*128);
}

// ---------------- projection GEMM: A staged as RAW F32 via global_load_lds ----------------
// BK=32, 16 K-tiles.  A converted f32->bf16 at fragment read (cvt_pk RNE).
// DUAL=1: one A-tile feeds Wk and Wv (two accumulators) — K read/staged once.
template<int DUAL>
__device__ __forceinline__ void proj_body(const float* __restrict__ A32, const ushort* __restrict__ B0w,
                                          const ushort* __restrict__ B1w,
                                          const float* __restrict__ bias0, const float* __restrict__ bias1,
                                          ushort* __restrict__ out0, ushort* __restrict__ vpT,
                                          char* lds, int m0, int n0, float os)
{
  const int t = threadIdx.x;
  const int w = t >> 6, lane = t & 63;
  const int wm = w >> 1, wn = w & 1;
  const int rA = lane & 15, g = lane >> 4;
  const int BUF = DUAL ? 49152 : 40960;

  const float* srcA[4]; int ldsA[4];
#pragma unroll
  for (int j = 0; j < 4; j++) {
    int Lb = (t + j*512) * 16;
    int U = Lb ^ (((Lb >> 7) & 7) << 4);
    srcA[j] = A32 + (size_t)(m0 + (U >> 7))*512 + ((U & 127) >> 2);
    ldsA[j] = Lb;
  }
  const ushort* srcB0; const ushort* srcB1; int ldsB;
  {
    int Lb = t * 16;
    int U = Lb ^ (((Lb >> 6) & 3) << 4);
    int row = U >> 6, col = (U & 63) >> 1;
    srcB0 = B0w + (size_t)(n0 + row)*512 + col;
    srcB1 = DUAL ? (B1w + (size_t)(n0 + row)*512 + col) : srcB0;
    ldsB = 32768 + Lb;
  }

#define PSTAGE(ti) do { char* bb_ = lds + ((ti) % 3) * BUF; \
    _Pragma("unroll") \
    for (int j = 0; j < 4; j++) gld16(bb_ + ldsA[j], srcA[j] + (ti)*32); \
    gld16(bb_ + ldsB, srcB0 + (ti)*32); \
    if (DUAL) gld16(bb_ + 8192 + ldsB, srcB1 + (ti)*32); } while (0)

  PSTAGE(0); PSTAGE(1);

  f32x4 acc0[4][4] = {};
  f32x4 acc1[4][4] = {};
  for (int i = 0; i < 16; i++) {
    if (i < 15) { if (DUAL) asm volatile("s_waitcnt vmcnt(6)" ::: "memory");
                  else      asm volatile("s_waitcnt vmcnt(5)" ::: "memory"); }
    else          asm volatile("s_waitcnt vmcnt(0)" ::: "memory");
    __builtin_amdgcn_s_barrier();
    __builtin_amdgcn_sched_barrier(0);
    const char* bufc = lds + (i % 3) * BUF;

    bf16x8 af[4];
#pragma unroll
    for (int m = 0; m < 4; m++) {
      int row = wm*64 + m*16 + rA;
      int o0 = (row*128 + g*32) ^ ((row & 7) << 4);
      f32x4 lo = *(const f32x4*)(bufc + o0);
      f32x4 hi = *(const f32x4*)(bufc + (o0 ^ 16));
      union { uint32_t u[4]; bf16x8 v; } af_;
      af_.u[0] = cvtpk(lo[0], lo[1]); af_.u[1] = cvtpk(lo[2], lo[3]);
      af_.u[2] = cvtpk(hi[0], hi[1]); af_.u[3] = cvtpk(hi[2], hi[3]);
      af[m] = af_.v;
    }
    bf16x8 bf0[4];
#pragma unroll
    for (int n = 0; n < 4; n++) {
      int row = wn*64 + n*16 + rA;
      bf0[n] = *(const bf16x8*)(bufc + 32768 + ((row*64 + g*16) ^ ((row & 3) << 4)));
    }
    if (i < 14) PSTAGE(i + 2);
    __builtin_amdgcn_sched_barrier(0);
    __builtin_amdgcn_s_setprio(1);
#pragma unroll
    for (int m = 0; m < 4; m++)
#pragma unroll
      for (int n = 0; n < 4; n++)
        acc0[m][n] = __builtin_amdgcn_mfma_f32_16x16x32_bf16(af[m], bf0[n], acc0[m][n], 0, 0, 0);
    __builtin_amdgcn_s_setprio(0);
    if (DUAL) {
      bf16x8 bf1[4];
#pragma unroll
      for (int n = 0; n < 4; n++) {
        int row = wn*64 + n*16 + rA;
        bf1[n] = *(const bf16x8*)(bufc + 40960 + ((row*64 + g*16) ^ ((row & 3) << 4)));
      }
      __builtin_amdgcn_s_setprio(1);
#pragma unroll
      for (int m = 0; m < 4; m++)
#pragma unroll
        for (int n = 0; n < 4; n++)
          acc1[m][n] = __builtin_amdgcn_mfma_f32_16x16x32_bf16(af[m], bf1[n], acc1[m][n], 0, 0, 0);
      __builtin_amdgcn_s_setprio(0);
    }
  }
#undef PSTAGE

#pragma unroll
  for (int m = 0; m < 4; m++)
#pragma unroll
    for (int n = 0; n < 4; n++) {
      int col = n0 + wn*64 + n*16 + rA;
      {
        float bb = bias0[col];
#pragma unroll
        for (int r = 0; r < 4; r++) {
          int row = m0 + wm*64 + m*16 + g*4 + r;
          out0[(size_t)row*512 + col] = f2b((acc0[m][n][r] + bb) * os);
        }
      }
      if (DUAL) {
        float bb = bias1[col];
        int b = m0 >> 9, k0 = m0 & 511;
        int hh = col >> 6, dl = col & 63;
        int kg = k0 + wm*64 + m*16 + g*4;
        float v0 = acc1[m][n][0] + bb, v1 = acc1[m][n][1] + bb;
        float v2 = acc1[m][n][2] + bb, v3 = acc1[m][n][3] + bb;
        uint2 pk;
        pk.x = (uint32_t)f2b(v0) | ((uint32_t)f2b(v1) << 16);
        pk.y = (uint32_t)f2b(v2) | ((uint32_t)f2b(v3) << 16);
        *(uint2*)(vpT + ((size_t)((b*8 + hh)*64 + dl)*512 + kg)) = pk;
      }
    }
}

__global__ __launch_bounds__(512, 1)
void k_projq(const float* __restrict__ Qf, const ushort* __restrict__ Wb,
             const float* __restrict__ bq, ushort* __restrict__ qp)
{
  __shared__ __align__(16) char lds[3*40960];   // 120 KB
  proj_body<0>(Qf, Wb, nullptr, bq, nullptr, qp, nullptr,
               lds, blockIdx.x*256, blockIdx.y*128, QSC_);
}

__global__ __launch_bounds__(512, 1)
void k_projkv(const float* __restrict__ Kf, const ushort* __restrict__ Wb,
              const float* __restrict__ bk, const float* __restrict__ bvv,
              ushort* __restrict__ kp, ushort* __restrict__ vpT)
{
  __shared__ __align__(16) char lds[3*49152];   // 144 KB
  proj_body<1>(Kf, Wb + (size_t)262144, Wb + 2*(size_t)262144, bk, bvv, kp, vpT,
               lds, blockIdx.x*256, blockIdx.y*128, 1.0f);
}

// ---------------- fused attention: zinv (pass1, 16x16) + PV (pass2, 32x32 in-register P,
//                  software-pipelined fragment prefetch; launch_bounds(512,1): LDS-bound
//                  at 1 block/CU anyway, so allow 256 VGPR for the pipeline) ----------------
__global__ __launch_bounds__(512, 1)
void k_att2(const ushort* __restrict__ qp, const ushort* __restrict__ kp,
            const ushort* __restrict__ vpT, float* __restrict__ zinv,
            ushort* __restrict__ attn)
{
  __shared__ __align__(16) char kt[65536];
  __shared__ __align__(16) char vt[65536];
  __shared__ __align__(16) char qpr[32768];
  int bh = blockIdx.x;
  int b = bh >> 3, h = bh & 7;
  int t = threadIdx.x, w = t >> 6, lane = t & 63;
  int rA = lane & 15, g = lane >> 4;
  const ushort* kbase = kp + (size_t)(b*512)*512 + h*64;
  const ushort* qbase = qp + (size_t)(b*512)*512 + h*64;
  const ushort* vbase = vpT + (size_t)bh*64*512;

#pragma unroll
  for (int i = 0; i < 8; i++) {          // K: [512][64] swizzled slot^(k&7)
    int c = i*512 + t; int row = c >> 3, sl = c & 7;
    gld16(kt + c*16, kbase + (size_t)row*512 + ((sl ^ (row & 7))*8));
  }
#define STAGE_Q(buf, qb) do { \
    _Pragma("unroll") \
    for (int i = 0; i < 2; i++) { \
      int c = i*512 + t; int row = c >> 3, sl = c & 7; \
      gld16(qpr + (buf)*16384 + c*16, \
            qbase + (size_t)((qb)*128 + row)*512 + ((sl ^ (row & 7))*8)); } } while (0)
  STAGE_Q(0, 0);
  STAGE_Q(1, 1);
#pragma unroll
  for (int i = 0; i < 8; i++) {          // V: [64][512] swizzled slot low3 ^ (d&7)
    int c = i*512 + t; int d = c >> 6, sl = c & 63;
    gld16(vt + c*16, vbase + (size_t)d*512 + ((sl ^ (d & 7))*8));
  }

  // ---- pass 1: zl[k] = 1/sum_q 2^s; wave owns k in [w*64, w*64+64) ----
  asm volatile("s_waitcnt vmcnt(10)" ::: "memory");   // K + Q0 landed (Q1,V in flight)
  __builtin_amdgcn_s_barrier();
  __builtin_amdgcn_sched_barrier(0);
  bf16x8 kf[4][2];
#pragma unroll
  for (int n = 0; n < 4; n++)
#pragma unroll
    for (int ks = 0; ks < 2; ks++) {
      int k = w*64 + n*16 + rA;
      kf[n][ks] = *(const bf16x8*)(kt + k*128 + (((ks*4 + g) ^ (k & 7))*16));
    }
  float Zacc[4] = {0.f, 0.f, 0.f, 0.f};
  for (int qb = 0; qb < 4; qb++) {
    if (qb == 1)      { asm volatile("s_waitcnt vmcnt(10)" ::: "memory"); }
    else if (qb == 2) { asm volatile("s_waitcnt vmcnt(2)" ::: "memory"); }
    else if (qb == 3) { asm volatile("s_waitcnt vmcnt(0)" ::: "memory"); }
    if (qb) { __builtin_amdgcn_s_barrier(); __builtin_amdgcn_sched_barrier(0); }
    const char* qtb = qpr + (qb & 1)*16384;
    f32x4 acc[8][4] = {};
#pragma unroll
    for (int ks = 0; ks < 2; ks++) {
      bf16x8 af[8];
#pragma unroll
      for (int m = 0; m < 8; m++) {
        int q = m*16 + rA;
        af[m] = *(const bf16x8*)(qtb + q*128 + (((ks*4 + g) ^ (q & 7))*16));
      }
      __builtin_amdgcn_s_setprio(1);
#pragma unroll
      for (int m = 0; m < 8; m++)
#pragma unroll
        for (int n = 0; n < 4; n++)
          acc[m][n] = __builtin_amdgcn_mfma_f32_16x16x32_bf16(af[m], kf[n][ks], acc[m][n], 0, 0, 0);
      __builtin_amdgcn_s_setprio(0);
    }
    if (qb < 3) __builtin_amdgcn_s_barrier();
    if (qb < 2) STAGE_Q(qb & 1, qb + 2);
#pragma unroll
    for (int m = 0; m < 8; m++)
#pragma unroll
      for (int n = 0; n < 4; n++) {
        float s = 0.f;
#pragma unroll
        for (int r = 0; r < 4; r++) s += ex2(acc[m][n][r]);
        Zacc[n] += s;
      }
  }
#undef STAGE_Q
#pragma unroll
  for (int n = 0; n < 4; n++) {
    float v = Zacc[n];
    v += __shfl_xor(v, 16);
    v += __shfl_xor(v, 32);
    if (lane < 16) ((float*)qpr)[w*64 + n*16 + lane] = 1.0f / v;   // zl handoff in LDS
  }
  __syncthreads();

  // ---- pass 2: 32x32x16, P in registers; wave owns q in [w*64, w*64+64).
  //      Software-pipelined: fragments for kc+1 issued before kc's MFMA clusters. ----
  const int l31 = lane & 31, hi5 = lane >> 5;
  bf16x8 qf2[2][4];
#pragma unroll
  for (int qb = 0; qb < 2; qb++)
#pragma unroll
    for (int ksd = 0; ksd < 4; ksd++)
      qf2[qb][ksd] = *(const bf16x8*)(qbase + (size_t)(w*64 + qb*32 + l31)*512 + ksd*16 + hi5*8);
  const float* zl = (const float*)qpr;
  f32x16 oacc[2][2] = {};

#define LOADF(kc, KF, VF, ZV) do { \
    int k_ = (kc)*32 + l31; \
    _Pragma("unroll") \
    for (int ksd = 0; ksd < 4; ksd++) \
      KF[ksd] = *(const bf16x8*)(kt + k_*128 + (((ksd*2 + hi5) ^ (k_ & 7))*16)); \
    _Pragma("unroll") \
    for (int db = 0; db < 2; db++) \
      _Pragma("unroll") \
      for (int ks = 0; ks < 2; ks++) { \
        int d_ = db*32 + l31; \
        VF[db*2 + ks] = *(const bf16x8*)(vt + d_*1024 + ((((kc)*4 + ks*2 + hi5) ^ (d_ & 7))*16)); \
      } \
    _Pragma("unroll") \
    for (int j = 0; j < 4; j++) ZV[j] = *(const f32x4*)(zl + (kc)*32 + j*8 + hi5*4); \
  } while (0)

#define COMPUTE(KF, VF, ZV) do { \
    _Pragma("unroll") \
    for (int qb = 0; qb < 2; qb++) { \
      f32x16 s = {}; \
      __builtin_amdgcn_s_setprio(1); \
      _Pragma("unroll") \
      for (int ksd = 0; ksd < 4; ksd++) \
        s = __builtin_amdgcn_mfma_f32_32x32x16_bf16(KF[ksd], qf2[qb][ksd], s, 0, 0, 0); \
      __builtin_amdgcn_s_setprio(0); \
      float e[16]; \
      _Pragma("unroll") \
      for (int r = 0; r < 16; r++) e[r] = ex2(s[r]) * ZV[r >> 2][r & 3]; \
      uint32_t x0 = cvtpk(e[0], e[1]),   y0 = cvtpk(e[4], e[5]); \
      uint32_t x1 = cvtpk(e[2], e[3]),   y1 = cvtpk(e[6], e[7]); \
      uint32_t x2 = cvtpk(e[8], e[9]),   y2 = cvtpk(e[12], e[13]); \
      uint32_t x3 = cvtpk(e[10], e[11]), y3 = cvtpk(e[14], e[15]); \
      uint2v r0 = __builtin_amdgcn_permlane32_swap(x0, y0, false, false); \
      uint2v r1 = __builtin_amdgcn_permlane32_swap(x1, y1, false, false); \
      uint2v r2 = __builtin_amdgcn_permlane32_swap(x2, y2, false, false); \
      uint2v r3 = __builtin_amdgcn_permlane32_swap(x3, y3, false, false); \
      union { uint32_t u[4]; bf16x8 v; } p0, p1; \
      p0.u[0] = r0[0]; p0.u[1] = r1[0]; p0.u[2] = r0[1]; p0.u[3] = r1[1]; \
      p1.u[0] = r2[0]; p1.u[1] = r3[0]; p1.u[2] = r2[1]; p1.u[3] = r3[1]; \
      __builtin_amdgcn_s_setprio(1); \
      _Pragma("unroll") \
      for (int db = 0; db < 2; db++) { \
        oacc[qb][db] = __builtin_amdgcn_mfma_f32_32x32x16_bf16(p0.v, VF[db*2 + 0], oacc[qb][db], 0, 0, 0); \
        oacc[qb][db] = __builtin_amdgcn_mfma_f32_32x32x16_bf16(p1.v, VF[db*2 + 1], oacc[qb][db], 0, 0, 0); \
      } \
      __builtin_amdgcn_s_setprio(0); \
    } \
  } while (0)

  bf16x8 kfA[4], kfB[4], vfA[4], vfB[4];
  f32x4 zvA[4], zvB[4];
  LOADF(0, kfA, vfA, zvA);
  for (int kc2 = 0; kc2 < 8; kc2++) {
    LOADF(2*kc2 + 1, kfB, vfB, zvB);
    COMPUTE(kfA, vfA, zvA);
    if (kc2 < 7) LOADF(2*kc2 + 2, kfA, vfA, zvA);
    COMPUTE(kfB, vfB, zvB);
  }
#undef LOADF
#undef COMPUTE

#pragma unroll
  for (int qb = 0; qb < 2; qb++)
#pragma unroll
    for (int db = 0; db < 2; db++)
#pragma unroll
      for (int r = 0; r < 16; r++) {
        int q = w*64 + qb*32 + (r & 3) + 8*(r >> 2) + 4*hi5;
        int d = db*32 + l31;
        attn[(size_t)(b*512 + q)*512 + h*64 + d] = f2b(oacc[qb][db][r]);
      }
}

// ---------------- host launcher ----------------
extern "C" void kernel_launch(void* const* d_in, const int* in_sizes, int n_in,
                              void* d_out, int out_size, void* d_ws, size_t ws_size,
                              hipStream_t stream) {
  const float* Q  = (const float*)d_in[0];
  const float* K  = (const float*)d_in[1];
  const float* Wq = (const float*)d_in[2];
  const float* bq = (const float*)d_in[3];
  const float* Wk = (const float*)d_in[4];
  const float* bk = (const float*)d_in[5];
  const float* Wv = (const float*)d_in[6];
  const float* bv = (const float*)d_in[7];
  const float* Wo = (const float*)d_in[8];
  const float* bo = (const float*)d_in[9];
  const float* W1 = (const float*)d_in[10];
  const float* b1 = (const float*)d_in[11];
  const float* W2 = (const float*)d_in[12];
  const float* b2 = (const float*)d_in[13];
  float* out = (float*)d_out;

  const size_t SZ = (size_t)16384 * 512;
  ushort* attn = (ushort*)d_ws;                 // slot 0
  ushort* outb = attn + SZ;                     // slot 1
  ushort* qp   = outb + SZ;
  ushort* kp   = qp + SZ;
  ushort* vpT  = kp + SZ;                       // v-projection, transposed; later reused as h1
  ushort* Wb   = vpT + SZ;
  float*  zinv = (float*)(Wb + 6 * (size_t)262144);
  ushort* h1   = vpT;

  k_cvtw<<<dim3(1536), dim3(256), 0, stream>>>(Wq, Wk, Wv, Wo, W1, W2, Wb);
  k_projq<<<dim3(64, 4), dim3(512), 0, stream>>>(Q, Wb, bq, qp);
  k_projkv<<<dim3(64, 4), dim3(512), 0, stream>>>(K, Wb, bk, bv, kp, vpT);
  k_att2<<<dim3(256), dim3(512), 0, stream>>>(qp, kp, vpT, zinv, attn);
  k_gemm<1><<<dim3(64, 4), dim3(512), 0, stream>>>(attn, Wb + 3*(size_t)262144, bo, Q, out, outb);
  k_gemm<2><<<dim3(64, 4), dim3(512), 0, stream>>>(outb, Wb + 4*(size_t)262144, b1, nullptr, nullptr, h1);
  k_gemm<3><<<dim3(64, 4), dim3(512), 0, stream>>>(h1, Wb + 5*(size_t)262144, b2, nullptr, out, nullptr);
}

// Round 17
// 139.776 us; speedup vs baseline: 1.0117x; 1.0117x over previous
//
#include <hip/hip_runtime.h>
#include <stdint.h>

// MAB block: B=32, N=512, D=512, H=8, dh=64.  M = B*N = 16384.
#define SCALE_ 0.044194173824159216f
// scale * log2(e): folded into the q-projection so attention uses exp2 directly.
#define QSC_ (0.044194173824159216f * 1.4426950408889634f)

typedef __attribute__((ext_vector_type(8))) short bf16x8;
typedef __attribute__((ext_vector_type(4))) float f32x4;
typedef __attribute__((ext_vector_type(16))) float f32x16;
typedef __attribute__((ext_vector_type(2))) unsigned int uint2v;

__device__ __forceinline__ ushort f2b(float f) {
  union { float f; uint32_t u; } v; v.f = f;
  return (ushort)((v.u + 0x7fffu + ((v.u >> 16) & 1u)) >> 16);  // RNE
}
__device__ __forceinline__ uint32_t cvtpk(float lo, float hi) {
  uint32_t r; asm("v_cvt_pk_bf16_f32 %0, %1, %2" : "=v"(r) : "v"(lo), "v"(hi)); return r;
}
__device__ __forceinline__ float ex2(float x) {          // 2^x (v_exp_f32)
  float r; asm("v_exp_f32 %0, %1" : "=v"(r) : "v"(x)); return r;
}
__device__ __forceinline__ void gld16(void* lds, const void* g) {
  __builtin_amdgcn_global_load_lds(
      (const __attribute__((address_space(1))) uint32_t*)g,
      (__attribute__((address_space(3))) uint32_t*)lds, 16, 0, 0);
}

// ---------------- fp32 -> bf16 convert (weights only) ----------------
__global__ __launch_bounds__(256)
void k_cvtw(const float* __restrict__ w0, const float* __restrict__ w1,
            const float* __restrict__ w2, const float* __restrict__ w3,
            const float* __restrict__ w4, const float* __restrict__ w5,
            ushort* __restrict__ Wb)
{
  const int NW = 262144;
  int i = (blockIdx.x * 256 + threadIdx.x) * 4;
  int seg = i >> 18;
  int off = i & (NW - 1);
  const float* src;
  switch (seg) { case 0: src = w0; break; case 1: src = w1; break; case 2: src = w2; break;
                 case 3: src = w3; break; case 4: src = w4; break; default: src = w5; }
  float4 v = *(const float4*)(src + off);
  ushort4 o = make_ushort4(f2b(v.x), f2b(v.y), f2b(v.z), f2b(v.w));
  *(ushort4*)(Wb + (size_t)seg * NW + off) = o;
}

// ---------------- tail GEMM: C = A(bf16,[M,512]) @ Bw(bf16,[512,512])^T ----------------
// 256x128 tile, BK=64, 8 waves, triple-buffered, counted vmcnt(6), slot swizzle.
// EPI: 1 = Q + (acc+bias) -> f32 + bf16   2 = relu->bf16   3 = out += acc+bias
template<int EPI>
__device__ __forceinline__ void gemm_body(const ushort* __restrict__ A, const ushort* __restrict__ Bw,
                                          const float* __restrict__ bias, const float* __restrict__ extra,
                                          float* __restrict__ outf, ushort* __restrict__ outb,
                                          char* lds, int m0, int n0)
{
  const int t = threadIdx.x;
  const int w = t >> 6, lane = t & 63;
  const int wm = w >> 1, wn = w & 1;
  const int rA = lane & 15, g = lane >> 4;

  const ushort* srcA[4]; int ldsA[4];
#pragma unroll
  for (int j = 0; j < 4; j++) {
    int L = (t + j*512) * 16;
    int U = L ^ (((L >> 7) & 7) << 4);
    srcA[j] = A + (size_t)(m0 + (U >> 7))*512 + ((U & 127) >> 1);
    ldsA[j] = L;
  }
  const ushort* srcB[2]; int ldsB[2];
#pragma unroll
  for (int j = 0; j < 2; j++) {
    int L = (t + j*512) * 16;
    int U = L ^ (((L >> 7) & 7) << 4);
    srcB[j] = Bw + (size_t)(n0 + (U >> 7))*512 + ((U & 127) >> 1);
    ldsB[j] = 32768 + L;
  }

#define STAGE_T(ti) do { char* bb_ = lds + ((ti) % 3) * 49152; \
    _Pragma("unroll") \
    for (int j = 0; j < 4; j++) gld16(bb_ + ldsA[j], srcA[j] + (ti)*64); \
    _Pragma("unroll") \
    for (int j = 0; j < 2; j++) gld16(bb_ + ldsB[j], srcB[j] + (ti)*64); } while (0)

  STAGE_T(0); STAGE_T(1);

  f32x4 acc[4][4] = {};
  for (int i = 0; i < 8; i++) {
    if (i < 7) asm volatile("s_waitcnt vmcnt(6)" ::: "memory");
    else       asm volatile("s_waitcnt vmcnt(0)" ::: "memory");
    __builtin_amdgcn_s_barrier();
    __builtin_amdgcn_sched_barrier(0);
    const char* bufc = lds + (i % 3) * 49152;

    bf16x8 afA[4], bfA[4], afB[4], bfB[4];
#pragma unroll
    for (int m = 0; m < 4; m++) {
      int row = wm*64 + m*16 + rA;
      afA[m] = *(const bf16x8*)(bufc + ((row*128 + g*16) ^ ((row & 7) << 4)));
      afB[m] = *(const bf16x8*)(bufc + ((row*128 + 64 + g*16) ^ ((row & 7) << 4)));
    }
#pragma unroll
    for (int n = 0; n < 4; n++) {
      int row = wn*64 + n*16 + rA;
      bfA[n] = *(const bf16x8*)(bufc + 32768 + ((row*128 + g*16) ^ ((row & 7) << 4)));
      bfB[n] = *(const bf16x8*)(bufc + 32768 + ((row*128 + 64 + g*16) ^ ((row & 7) << 4)));
    }
    if (i < 6) STAGE_T(i + 2);
    __builtin_amdgcn_sched_barrier(0);
    __builtin_amdgcn_s_setprio(1);
#pragma unroll
    for (int m = 0; m < 4; m++)
#pragma unroll
      for (int n = 0; n < 4; n++)
        acc[m][n] = __builtin_amdgcn_mfma_f32_16x16x32_bf16(afA[m], bfA[n], acc[m][n], 0, 0, 0);
#pragma unroll
    for (int m = 0; m < 4; m++)
#pragma unroll
      for (int n = 0; n < 4; n++)
        acc[m][n] = __builtin_amdgcn_mfma_f32_16x16x32_bf16(afB[m], bfB[n], acc[m][n], 0, 0, 0);
    __builtin_amdgcn_s_setprio(0);
  }
#undef STAGE_T

#pragma unroll
  for (int m = 0; m < 4; m++)
#pragma unroll
    for (int n = 0; n < 4; n++) {
      int col = n0 + wn*64 + n*16 + rA;
      float bb = bias[col];
#pragma unroll
      for (int r = 0; r < 4; r++) {
        int row = m0 + wm*64 + m*16 + g*4 + r;
        size_t idx = (size_t)row*512 + col;
        float v = acc[m][n][r] + bb;
        if (EPI == 1)      { float o = extra[idx] + v; outf[idx] = o; outb[idx] = f2b(o); }
        else if (EPI == 2) outb[idx] = f2b(v > 0.f ? v : 0.f);
        else               outf[idx] += v;
      }
    }
}

template<int EPI>
__global__ __launch_bounds__(512, 2)
void k_gemm(const ushort* __restrict__ A, const ushort* __restrict__ Bw,
            const float* __restrict__ bias, const float* __restrict__ extra,
            float* __restrict__ outf, ushort* __restrict__ outb)
{
  __shared__ __align__(16) char lds[3*49152];   // 144 KB
  gemm_body<EPI>(A, Bw, bias, extra, outf, outb, lds, blockIdx.x*256, blockIdx.y*128);
}

// ---------------- projection GEMM: A staged as RAW F32 via global_load_lds ----------------
// BK=32, 16 K-tiles.  A converted f32->bf16 at fragment read (cvt_pk RNE).
// DUAL=1: one A-tile feeds Wk and Wv (two accumulators) — K read/staged once.
template<int DUAL>
__device__ __forceinline__ void proj_body(const float* __restrict__ A32, const ushort* __restrict__ B0w,
                                          const ushort* __restrict__ B1w,
                                          const float* __restrict__ bias0, const float* __restrict__ bias1,
                                          ushort* __restrict__ out0, ushort* __restrict__ vpT,
                                          char* lds, int m0, int n0, float os)
{
  const int t = threadIdx.x;
  const int w = t >> 6, lane = t & 63;
  const int wm = w >> 1, wn = w & 1;
  const int rA = lane & 15, g = lane >> 4;
  const int BUF = DUAL ? 49152 : 40960;

  const float* srcA[4]; int ldsA[4];
#pragma unroll
  for (int j = 0; j < 4; j++) {
    int Lb = (t + j*512) * 16;
    int U = Lb ^ (((Lb >> 7) & 7) << 4);
    srcA[j] = A32 + (size_t)(m0 + (U >> 7))*512 + ((U & 127) >> 2);
    ldsA[j] = Lb;
  }
  const ushort* srcB0; const ushort* srcB1; int ldsB;
  {
    int Lb = t * 16;
    int U = Lb ^ (((Lb >> 6) & 3) << 4);
    int row = U >> 6, col = (U & 63) >> 1;
    srcB0 = B0w + (size_t)(n0 + row)*512 + col;
    srcB1 = DUAL ? (B1w + (size_t)(n0 + row)*512 + col) : srcB0;
    ldsB = 32768 + Lb;
  }

#define PSTAGE(ti) do { char* bb_ = lds + ((ti) % 3) * BUF; \
    _Pragma("unroll") \
    for (int j = 0; j < 4; j++) gld16(bb_ + ldsA[j], srcA[j] + (ti)*32); \
    gld16(bb_ + ldsB, srcB0 + (ti)*32); \
    if (DUAL) gld16(bb_ + 8192 + ldsB, srcB1 + (ti)*32); } while (0)

  PSTAGE(0); PSTAGE(1);

  f32x4 acc0[4][4] = {};
  f32x4 acc1[4][4] = {};
  for (int i = 0; i < 16; i++) {
    if (i < 15) { if (DUAL) asm volatile("s_waitcnt vmcnt(6)" ::: "memory");
                  else      asm volatile("s_waitcnt vmcnt(5)" ::: "memory"); }
    else          asm volatile("s_waitcnt vmcnt(0)" ::: "memory");
    __builtin_amdgcn_s_barrier();
    __builtin_amdgcn_sched_barrier(0);
    const char* bufc = lds + (i % 3) * BUF;

    bf16x8 af[4];
#pragma unroll
    for (int m = 0; m < 4; m++) {
      int row = wm*64 + m*16 + rA;
      int o0 = (row*128 + g*32) ^ ((row & 7) << 4);
      f32x4 lo = *(const f32x4*)(bufc + o0);
      f32x4 hi = *(const f32x4*)(bufc + (o0 ^ 16));
      union { uint32_t u[4]; bf16x8 v; } af_;
      af_.u[0] = cvtpk(lo[0], lo[1]); af_.u[1] = cvtpk(lo[2], lo[3]);
      af_.u[2] = cvtpk(hi[0], hi[1]); af_.u[3] = cvtpk(hi[2], hi[3]);
      af[m] = af_.v;
    }
    bf16x8 bf0[4];
#pragma unroll
    for (int n = 0; n < 4; n++) {
      int row = wn*64 + n*16 + rA;
      bf0[n] = *(const bf16x8*)(bufc + 32768 + ((row*64 + g*16) ^ ((row & 3) << 4)));
    }
    if (i < 14) PSTAGE(i + 2);
    __builtin_amdgcn_sched_barrier(0);
    __builtin_amdgcn_s_setprio(1);
#pragma unroll
    for (int m = 0; m < 4; m++)
#pragma unroll
      for (int n = 0; n < 4; n++)
        acc0[m][n] = __builtin_amdgcn_mfma_f32_16x16x32_bf16(af[m], bf0[n], acc0[m][n], 0, 0, 0);
    __builtin_amdgcn_s_setprio(0);
    if (DUAL) {
      bf16x8 bf1[4];
#pragma unroll
      for (int n = 0; n < 4; n++) {
        int row = wn*64 + n*16 + rA;
        bf1[n] = *(const bf16x8*)(bufc + 40960 + ((row*64 + g*16) ^ ((row & 3) << 4)));
      }
      __builtin_amdgcn_s_setprio(1);
#pragma unroll
      for (int m = 0; m < 4; m++)
#pragma unroll
        for (int n = 0; n < 4; n++)
          acc1[m][n] = __builtin_amdgcn_mfma_f32_16x16x32_bf16(af[m], bf1[n], acc1[m][n], 0, 0, 0);
      __builtin_amdgcn_s_setprio(0);
    }
  }
#undef PSTAGE

#pragma unroll
  for (int m = 0; m < 4; m++)
#pragma unroll
    for (int n = 0; n < 4; n++) {
      int col = n0 + wn*64 + n*16 + rA;
      {
        float bb = bias0[col];
#pragma unroll
        for (int r = 0; r < 4; r++) {
          int row = m0 + wm*64 + m*16 + g*4 + r;
          out0[(size_t)row*512 + col] = f2b((acc0[m][n][r] + bb) * os);
        }
      }
      if (DUAL) {
        float bb = bias1[col];
        int b = m0 >> 9, k0 = m0 & 511;
        int hh = col >> 6, dl = col & 63;
        int kg = k0 + wm*64 + m*16 + g*4;
        float v0 = acc1[m][n][0] + bb, v1 = acc1[m][n][1] + bb;
        float v2 = acc1[m][n][2] + bb, v3 = acc1[m][n][3] + bb;
        uint2 pk;
        pk.x = (uint32_t)f2b(v0) | ((uint32_t)f2b(v1) << 16);
        pk.y = (uint32_t)f2b(v2) | ((uint32_t)f2b(v3) << 16);
        *(uint2*)(vpT + ((size_t)((b*8 + hh)*64 + dl)*512 + kg)) = pk;
      }
    }
}

// merged projection dispatch: z=0 -> Q-proj (scaled), z=1 -> fused K/V-proj.
// One dispatch = no inter-dispatch drain bubble; idle CUs from the Q slice
// immediately pick up KV blocks.
__global__ __launch_bounds__(512, 1)
void k_proj(const float* __restrict__ Qf, const float* __restrict__ Kf,
            const ushort* __restrict__ Wb,
            const float* __restrict__ bq, const float* __restrict__ bk,
            const float* __restrict__ bvv,
            ushort* __restrict__ qp, ushort* __restrict__ kp, ushort* __restrict__ vpT)
{
  __shared__ __align__(16) char lds[3*49152];   // 144 KB (covers both bodies)
  if (blockIdx.z == 0) {
    proj_body<0>(Qf, Wb, nullptr, bq, nullptr, qp, nullptr,
                 lds, blockIdx.x*256, blockIdx.y*128, QSC_);
  } else {
    proj_body<1>(Kf, Wb + (size_t)262144, Wb + 2*(size_t)262144, bk, bvv, kp, vpT,
                 lds, blockIdx.x*256, blockIdx.y*128, 1.0f);
  }
}

// ---------------- fused attention: zinv (pass1, 16x16) + PV (pass2, 32x32 in-register P,
//                  software-pipelined fragment prefetch) ----------------
__global__ __launch_bounds__(512, 1)
void k_att2(const ushort* __restrict__ qp, const ushort* __restrict__ kp,
            const ushort* __restrict__ vpT, float* __restrict__ zinv,
            ushort* __restrict__ attn)
{
  __shared__ __align__(16) char kt[65536];
  __shared__ __align__(16) char vt[65536];
  __shared__ __align__(16) char qpr[32768];
  int bh = blockIdx.x;
  int b = bh >> 3, h = bh & 7;
  int t = threadIdx.x, w = t >> 6, lane = t & 63;
  int rA = lane & 15, g = lane >> 4;
  const ushort* kbase = kp + (size_t)(b*512)*512 + h*64;
  const ushort* qbase = qp + (size_t)(b*512)*512 + h*64;
  const ushort* vbase = vpT + (size_t)bh*64*512;

#pragma unroll
  for (int i = 0; i < 8; i++) {          // K: [512][64] swizzled slot^(k&7)
    int c = i*512 + t; int row = c >> 3, sl = c & 7;
    gld16(kt + c*16, kbase + (size_t)row*512 + ((sl ^ (row & 7))*8));
  }
#define STAGE_Q(buf, qb) do { \
    _Pragma("unroll") \
    for (int i = 0; i < 2; i++) { \
      int c = i*512 + t; int row = c >> 3, sl = c & 7; \
      gld16(qpr + (buf)*16384 + c*16, \
            qbase + (size_t)((qb)*128 + row)*512 + ((sl ^ (row & 7))*8)); } } while (0)
  STAGE_Q(0, 0);
  STAGE_Q(1, 1);
#pragma unroll
  for (int i = 0; i < 8; i++) {          // V: [64][512] swizzled slot low3 ^ (d&7)
    int c = i*512 + t; int d = c >> 6, sl = c & 63;
    gld16(vt + c*16, vbase + (size_t)d*512 + ((sl ^ (d & 7))*8));
  }

  // ---- pass 1: zl[k] = 1/sum_q 2^s; wave owns k in [w*64, w*64+64) ----
  asm volatile("s_waitcnt vmcnt(10)" ::: "memory");   // K + Q0 landed (Q1,V in flight)
  __builtin_amdgcn_s_barrier();
  __builtin_amdgcn_sched_barrier(0);
  bf16x8 kf[4][2];
#pragma unroll
  for (int n = 0; n < 4; n++)
#pragma unroll
    for (int ks = 0; ks < 2; ks++) {
      int k = w*64 + n*16 + rA;
      kf[n][ks] = *(const bf16x8*)(kt + k*128 + (((ks*4 + g) ^ (k & 7))*16));
    }
  float Zacc[4] = {0.f, 0.f, 0.f, 0.f};
  for (int qb = 0; qb < 4; qb++) {
    if (qb == 1)      { asm volatile("s_waitcnt vmcnt(10)" ::: "memory"); }
    else if (qb == 2) { asm volatile("s_waitcnt vmcnt(2)" ::: "memory"); }
    else if (qb == 3) { asm volatile("s_waitcnt vmcnt(0)" ::: "memory"); }
    if (qb) { __builtin_amdgcn_s_barrier(); __builtin_amdgcn_sched_barrier(0); }
    const char* qtb = qpr + (qb & 1)*16384;
    f32x4 acc[8][4] = {};
#pragma unroll
    for (int ks = 0; ks < 2; ks++) {
      bf16x8 af[8];
#pragma unroll
      for (int m = 0; m < 8; m++) {
        int q = m*16 + rA;
        af[m] = *(const bf16x8*)(qtb + q*128 + (((ks*4 + g) ^ (q & 7))*16));
      }
      __builtin_amdgcn_s_setprio(1);
#pragma unroll
      for (int m = 0; m < 8; m++)
#pragma unroll
        for (int n = 0; n < 4; n++)
          acc[m][n] = __builtin_amdgcn_mfma_f32_16x16x32_bf16(af[m], kf[n][ks], acc[m][n], 0, 0, 0);
      __builtin_amdgcn_s_setprio(0);
    }
    if (qb < 3) __builtin_amdgcn_s_barrier();
    if (qb < 2) STAGE_Q(qb & 1, qb + 2);
#pragma unroll
    for (int m = 0; m < 8; m++)
#pragma unroll
      for (int n = 0; n < 4; n++) {
        float s = 0.f;
#pragma unroll
        for (int r = 0; r < 4; r++) s += ex2(acc[m][n][r]);
        Zacc[n] += s;
      }
  }
#undef STAGE_Q
#pragma unroll
  for (int n = 0; n < 4; n++) {
    float v = Zacc[n];
    v += __shfl_xor(v, 16);
    v += __shfl_xor(v, 32);
    if (lane < 16) ((float*)qpr)[w*64 + n*16 + lane] = 1.0f / v;   // zl handoff in LDS
  }
  __syncthreads();

  // ---- pass 2: 32x32x16, P in registers; wave owns q in [w*64, w*64+64).
  //      Software-pipelined: fragments for kc+1 issued before kc's MFMA clusters. ----
  const int l31 = lane & 31, hi5 = lane >> 5;
  bf16x8 qf2[2][4];
#pragma unroll
  for (int qb = 0; qb < 2; qb++)
#pragma unroll
    for (int ksd = 0; ksd < 4; ksd++)
      qf2[qb][ksd] = *(const bf16x8*)(qbase + (size_t)(w*64 + qb*32 + l31)*512 + ksd*16 + hi5*8);
  const float* zl = (const float*)qpr;
  f32x16 oacc[2][2] = {};

#define LOADF(kc, KF, VF, ZV) do { \
    int k_ = (kc)*32 + l31; \
    _Pragma("unroll") \
    for (int ksd = 0; ksd < 4; ksd++) \
      KF[ksd] = *(const bf16x8*)(kt + k_*128 + (((ksd*2 + hi5) ^ (k_ & 7))*16)); \
    _Pragma("unroll") \
    for (int db = 0; db < 2; db++) \
      _Pragma("unroll") \
      for (int ks = 0; ks < 2; ks++) { \
        int d_ = db*32 + l31; \
        VF[db*2 + ks] = *(const bf16x8*)(vt + d_*1024 + ((((kc)*4 + ks*2 + hi5) ^ (d_ & 7))*16)); \
      } \
    _Pragma("unroll") \
    for (int j = 0; j < 4; j++) ZV[j] = *(const f32x4*)(zl + (kc)*32 + j*8 + hi5*4); \
  } while (0)

#define COMPUTE(KF, VF, ZV) do { \
    _Pragma("unroll") \
    for (int qb = 0; qb < 2; qb++) { \
      f32x16 s = {}; \
      __builtin_amdgcn_s_setprio(1); \
      _Pragma("unroll") \
      for (int ksd = 0; ksd < 4; ksd++) \
        s = __builtin_amdgcn_mfma_f32_32x32x16_bf16(KF[ksd], qf2[qb][ksd], s, 0, 0, 0); \
      __builtin_amdgcn_s_setprio(0); \
      float e[16]; \
      _Pragma("unroll") \
      for (int r = 0; r < 16; r++) e[r] = ex2(s[r]) * ZV[r >> 2][r & 3]; \
      uint32_t x0 = cvtpk(e[0], e[1]),   y0 = cvtpk(e[4], e[5]); \
      uint32_t x1 = cvtpk(e[2], e[3]),   y1 = cvtpk(e[6], e[7]); \
      uint32_t x2 = cvtpk(e[8], e[9]),   y2 = cvtpk(e[12], e[13]); \
      uint32_t x3 = cvtpk(e[10], e[11]), y3 = cvtpk(e[14], e[15]); \
      uint2v r0 = __builtin_amdgcn_permlane32_swap(x0, y0, false, false); \
      uint2v r1 = __builtin_amdgcn_permlane32_swap(x1, y1, false, false); \
      uint2v r2 = __builtin_amdgcn_permlane32_swap(x2, y2, false, false); \
      uint2v r3 = __builtin_amdgcn_permlane32_swap(x3, y3, false, false); \
      union { uint32_t u[4]; bf16x8 v; } p0, p1; \
      p0.u[0] = r0[0]; p0.u[1] = r1[0]; p0.u[2] = r0[1]; p0.u[3] = r1[1]; \
      p1.u[0] = r2[0]; p1.u[1] = r3[0]; p1.u[2] = r2[1]; p1.u[3] = r3[1]; \
      __builtin_amdgcn_s_setprio(1); \
      _Pragma("unroll") \
      for (int db = 0; db < 2; db++) { \
        oacc[qb][db] = __builtin_amdgcn_mfma_f32_32x32x16_bf16(p0.v, VF[db*2 + 0], oacc[qb][db], 0, 0, 0); \
        oacc[qb][db] = __builtin_amdgcn_mfma_f32_32x32x16_bf16(p1.v, VF[db*2 + 1], oacc[qb][db], 0, 0, 0); \
      } \
      __builtin_amdgcn_s_setprio(0); \
    } \
  } while (0)

  bf16x8 kfA[4], kfB[4], vfA[4], vfB[4];
  f32x4 zvA[4], zvB[4];
  LOADF(0, kfA, vfA, zvA);
  for (int kc2 = 0; kc2 < 8; kc2++) {
    LOADF(2*kc2 + 1, kfB, vfB, zvB);
    COMPUTE(kfA, vfA, zvA);
    if (kc2 < 7) LOADF(2*kc2 + 2, kfA, vfA, zvA);
    COMPUTE(kfB, vfB, zvB);
  }
#undef LOADF
#undef COMPUTE

#pragma unroll
  for (int qb = 0; qb < 2; qb++)
#pragma unroll
    for (int db = 0; db < 2; db++)
#pragma unroll
      for (int r = 0; r < 16; r++) {
        int q = w*64 + qb*32 + (r & 3) + 8*(r >> 2) + 4*hi5;
        int d = db*32 + l31;
        attn[(size_t)(b*512 + q)*512 + h*64 + d] = f2b(oacc[qb][db][r]);
      }
}

// ---------------- host launcher ----------------
extern "C" void kernel_launch(void* const* d_in, const int* in_sizes, int n_in,
                              void* d_out, int out_size, void* d_ws, size_t ws_size,
                              hipStream_t stream) {
  const float* Q  = (const float*)d_in[0];
  const float* K  = (const float*)d_in[1];
  const float* Wq = (const float*)d_in[2];
  const float* bq = (const float*)d_in[3];
  const float* Wk = (const float*)d_in[4];
  const float* bk = (const float*)d_in[5];
  const float* Wv = (const float*)d_in[6];
  const float* bv = (const float*)d_in[7];
  const float* Wo = (const float*)d_in[8];
  const float* bo = (const float*)d_in[9];
  const float* W1 = (const float*)d_in[10];
  const float* b1 = (const float*)d_in[11];
  const float* W2 = (const float*)d_in[12];
  const float* b2 = (const float*)d_in[13];
  float* out = (float*)d_out;

  const size_t SZ = (size_t)16384 * 512;
  ushort* attn = (ushort*)d_ws;                 // slot 0
  ushort* outb = attn + SZ;                     // slot 1
  ushort* qp   = outb + SZ;
  ushort* kp   = qp + SZ;
  ushort* vpT  = kp + SZ;                       // v-projection, transposed; later reused as h1
  ushort* Wb   = vpT + SZ;
  float*  zinv = (float*)(Wb + 6 * (size_t)262144);
  ushort* h1   = vpT;

  k_cvtw<<<dim3(1536), dim3(256), 0, stream>>>(Wq, Wk, Wv, Wo, W1, W2, Wb);
  k_proj<<<dim3(64, 4, 2), dim3(512), 0, stream>>>(Q, K, Wb, bq, bk, bv, qp, kp, vpT);
  k_att2<<<dim3(256), dim3(512), 0, stream>>>(qp, kp, vpT, zinv, attn);
  k_gemm<1><<<dim3(64, 4), dim3(512), 0, stream>>>(attn, Wb + 3*(size_t)262144, bo, Q, out, outb);
  k_gemm<2><<<dim3(64, 4), dim3(512), 0, stream>>>(outb, Wb + 4*(size_t)262144, b1, nullptr, nullptr, h1);
  k_gemm<3><<<dim3(64, 4), dim3(512), 0, stream>>>(h1, Wb + 5*(size_t)262144, b2, nullptr, out, nullptr);
}

// Round 18
// 138.865 us; speedup vs baseline: 1.0183x; 1.0066x over previous
//
#include <hip/hip_runtime.h>
#include <stdint.h>

// MAB block: B=32, N=512, D=512, H=8, dh=64.  M = B*N = 16384.
#define SCALE_ 0.044194173824159216f
// scale * log2(e): folded into the q-projection so attention uses exp2 directly.
#define QSC_ (0.044194173824159216f * 1.4426950408889634f)

typedef __attribute__((ext_vector_type(8))) short bf16x8;
typedef __attribute__((ext_vector_type(4))) float f32x4;
typedef __attribute__((ext_vector_type(16))) float f32x16;
typedef __attribute__((ext_vector_type(2))) unsigned int uint2v;

__device__ __forceinline__ ushort f2b(float f) {
  union { float f; uint32_t u; } v; v.f = f;
  return (ushort)((v.u + 0x7fffu + ((v.u >> 16) & 1u)) >> 16);  // RNE
}
__device__ __forceinline__ uint32_t cvtpk(float lo, float hi) {
  uint32_t r; asm("v_cvt_pk_bf16_f32 %0, %1, %2" : "=v"(r) : "v"(lo), "v"(hi)); return r;
}
__device__ __forceinline__ float ex2(float x) {          // 2^x (v_exp_f32)
  float r; asm("v_exp_f32 %0, %1" : "=v"(r) : "v"(x)); return r;
}
__device__ __forceinline__ void gld16(void* lds, const void* g) {
  __builtin_amdgcn_global_load_lds(
      (const __attribute__((address_space(1))) uint32_t*)g,
      (__attribute__((address_space(3))) uint32_t*)lds, 16, 0, 0);
}

// ---------------- fp32 -> bf16 convert (weights only) ----------------
__global__ __launch_bounds__(256)
void k_cvtw(const float* __restrict__ w0, const float* __restrict__ w1,
            const float* __restrict__ w2, const float* __restrict__ w3,
            const float* __restrict__ w4, const float* __restrict__ w5,
            ushort* __restrict__ Wb)
{
  const int NW = 262144;
  int i = (blockIdx.x * 256 + threadIdx.x) * 4;
  int seg = i >> 18;
  int off = i & (NW - 1);
  const float* src;
  switch (seg) { case 0: src = w0; break; case 1: src = w1; break; case 2: src = w2; break;
                 case 3: src = w3; break; case 4: src = w4; break; default: src = w5; }
  float4 v = *(const float4*)(src + off);
  ushort4 o = make_ushort4(f2b(v.x), f2b(v.y), f2b(v.z), f2b(v.w));
  *(ushort4*)(Wb + (size_t)seg * NW + off) = o;
}

// ---------------- tail GEMM: C = A(bf16,[M,512]) @ Bw(bf16,[512,512])^T ----------------
// 256x128 tile, BK=64, 8 waves, triple-buffered, counted vmcnt(6), slot swizzle.
// EPI: 1 = Q + (acc+bias) -> f32 + bf16   2 = relu->bf16   3 = out += acc+bias
template<int EPI>
__device__ __forceinline__ void gemm_body(const ushort* __restrict__ A, const ushort* __restrict__ Bw,
                                          const float* __restrict__ bias, const float* __restrict__ extra,
                                          float* __restrict__ outf, ushort* __restrict__ outb,
                                          char* lds, int m0, int n0)
{
  const int t = threadIdx.x;
  const int w = t >> 6, lane = t & 63;
  const int wm = w >> 1, wn = w & 1;
  const int rA = lane & 15, g = lane >> 4;

  const ushort* srcA[4]; int ldsA[4];
#pragma unroll
  for (int j = 0; j < 4; j++) {
    int L = (t + j*512) * 16;
    int U = L ^ (((L >> 7) & 7) << 4);
    srcA[j] = A + (size_t)(m0 + (U >> 7))*512 + ((U & 127) >> 1);
    ldsA[j] = L;
  }
  const ushort* srcB[2]; int ldsB[2];
#pragma unroll
  for (int j = 0; j < 2; j++) {
    int L = (t + j*512) * 16;
    int U = L ^ (((L >> 7) & 7) << 4);
    srcB[j] = Bw + (size_t)(n0 + (U >> 7))*512 + ((U & 127) >> 1);
    ldsB[j] = 32768 + L;
  }

#define STAGE_T(ti) do { char* bb_ = lds + ((ti) % 3) * 49152; \
    _Pragma("unroll") \
    for (int j = 0; j < 4; j++) gld16(bb_ + ldsA[j], srcA[j] + (ti)*64); \
    _Pragma("unroll") \
    for (int j = 0; j < 2; j++) gld16(bb_ + ldsB[j], srcB[j] + (ti)*64); } while (0)

  STAGE_T(0); STAGE_T(1);

  f32x4 acc[4][4] = {};
  for (int i = 0; i < 8; i++) {
    if (i < 7) asm volatile("s_waitcnt vmcnt(6)" ::: "memory");
    else       asm volatile("s_waitcnt vmcnt(0)" ::: "memory");
    __builtin_amdgcn_s_barrier();
    __builtin_amdgcn_sched_barrier(0);
    const char* bufc = lds + (i % 3) * 49152;

    bf16x8 afA[4], bfA[4], afB[4], bfB[4];
#pragma unroll
    for (int m = 0; m < 4; m++) {
      int row = wm*64 + m*16 + rA;
      afA[m] = *(const bf16x8*)(bufc + ((row*128 + g*16) ^ ((row & 7) << 4)));
      afB[m] = *(const bf16x8*)(bufc + ((row*128 + 64 + g*16) ^ ((row & 7) << 4)));
    }
#pragma unroll
    for (int n = 0; n < 4; n++) {
      int row = wn*64 + n*16 + rA;
      bfA[n] = *(const bf16x8*)(bufc + 32768 + ((row*128 + g*16) ^ ((row & 7) << 4)));
      bfB[n] = *(const bf16x8*)(bufc + 32768 + ((row*128 + 64 + g*16) ^ ((row & 7) << 4)));
    }
    if (i < 6) STAGE_T(i + 2);
    __builtin_amdgcn_sched_barrier(0);
    __builtin_amdgcn_s_setprio(1);
#pragma unroll
    for (int m = 0; m < 4; m++)
#pragma unroll
      for (int n = 0; n < 4; n++)
        acc[m][n] = __builtin_amdgcn_mfma_f32_16x16x32_bf16(afA[m], bfA[n], acc[m][n], 0, 0, 0);
#pragma unroll
    for (int m = 0; m < 4; m++)
#pragma unroll
      for (int n = 0; n < 4; n++)
        acc[m][n] = __builtin_amdgcn_mfma_f32_16x16x32_bf16(afB[m], bfB[n], acc[m][n], 0, 0, 0);
    __builtin_amdgcn_s_setprio(0);
  }
#undef STAGE_T

#pragma unroll
  for (int m = 0; m < 4; m++)
#pragma unroll
    for (int n = 0; n < 4; n++) {
      int col = n0 + wn*64 + n*16 + rA;
      float bb = bias[col];
#pragma unroll
      for (int r = 0; r < 4; r++) {
        int row = m0 + wm*64 + m*16 + g*4 + r;
        size_t idx = (size_t)row*512 + col;
        float v = acc[m][n][r] + bb;
        if (EPI == 1)      { float o = extra[idx] + v; outf[idx] = o; outb[idx] = f2b(o); }
        else if (EPI == 2) outb[idx] = f2b(v > 0.f ? v : 0.f);
        else               outf[idx] += v;
      }
    }
}

template<int EPI>
__global__ __launch_bounds__(512, 2)
void k_gemm(const ushort* __restrict__ A, const ushort* __restrict__ Bw,
            const float* __restrict__ bias, const float* __restrict__ extra,
            float* __restrict__ outf, ushort* __restrict__ outb)
{
  __shared__ __align__(16) char lds[3*49152];   // 144 KB
  gemm_body<EPI>(A, Bw, bias, extra, outf, outb, lds, blockIdx.x*256, blockIdx.y*128);
}

// ---------------- projection GEMM: A staged as RAW F32 via global_load_lds ----------------
// BK=32, 16 K-tiles.  A converted f32->bf16 at fragment read (cvt_pk RNE).
// DUAL=1: one A-tile feeds Wk and Wv (two accumulators) — K read/staged once.
// B tile rows are 64B: slot swizzle must use (row>>1)&3 (bit0 of row selects the
// 32-bank half via the row base) -> even rows hit quads 0-3, odd rows 4-7,
// 2 lanes/quad = conflict-free.  ((row&3) was 4-way: rows 0,4,8,12 same quad.)
template<int DUAL>
__device__ __forceinline__ void proj_body(const float* __restrict__ A32, const ushort* __restrict__ B0w,
                                          const ushort* __restrict__ B1w,
                                          const float* __restrict__ bias0, const float* __restrict__ bias1,
                                          ushort* __restrict__ out0, ushort* __restrict__ vpT,
                                          char* lds, int m0, int n0, float os)
{
  const int t = threadIdx.x;
  const int w = t >> 6, lane = t & 63;
  const int wm = w >> 1, wn = w & 1;
  const int rA = lane & 15, g = lane >> 4;
  const int BUF = DUAL ? 49152 : 40960;

  const float* srcA[4]; int ldsA[4];
#pragma unroll
  for (int j = 0; j < 4; j++) {
    int Lb = (t + j*512) * 16;
    int U = Lb ^ (((Lb >> 7) & 7) << 4);
    srcA[j] = A32 + (size_t)(m0 + (U >> 7))*512 + ((U & 127) >> 2);
    ldsA[j] = Lb;
  }
  const ushort* srcB0; const ushort* srcB1; int ldsB;
  {
    int Lb = t * 16;
    int U = Lb ^ (((Lb >> 7) & 3) << 4);     // involution: bits 4-5 ^= bits 7-8 (row>>1)
    int row = U >> 6, col = (U & 63) >> 1;
    srcB0 = B0w + (size_t)(n0 + row)*512 + col;
    srcB1 = DUAL ? (B1w + (size_t)(n0 + row)*512 + col) : srcB0;
    ldsB = 32768 + Lb;
  }

#define PSTAGE(ti) do { char* bb_ = lds + ((ti) % 3) * BUF; \
    _Pragma("unroll") \
    for (int j = 0; j < 4; j++) gld16(bb_ + ldsA[j], srcA[j] + (ti)*32); \
    gld16(bb_ + ldsB, srcB0 + (ti)*32); \
    if (DUAL) gld16(bb_ + 8192 + ldsB, srcB1 + (ti)*32); } while (0)

  PSTAGE(0); PSTAGE(1);

  f32x4 acc0[4][4] = {};
  f32x4 acc1[4][4] = {};
  for (int i = 0; i < 16; i++) {
    if (i < 15) { if (DUAL) asm volatile("s_waitcnt vmcnt(6)" ::: "memory");
                  else      asm volatile("s_waitcnt vmcnt(5)" ::: "memory"); }
    else          asm volatile("s_waitcnt vmcnt(0)" ::: "memory");
    __builtin_amdgcn_s_barrier();
    __builtin_amdgcn_sched_barrier(0);
    const char* bufc = lds + (i % 3) * BUF;

    bf16x8 af[4];
#pragma unroll
    for (int m = 0; m < 4; m++) {
      int row = wm*64 + m*16 + rA;
      int o0 = (row*128 + g*32) ^ ((row & 7) << 4);
      f32x4 lo = *(const f32x4*)(bufc + o0);
      f32x4 hi = *(const f32x4*)(bufc + (o0 ^ 16));
      union { uint32_t u[4]; bf16x8 v; } af_;
      af_.u[0] = cvtpk(lo[0], lo[1]); af_.u[1] = cvtpk(lo[2], lo[3]);
      af_.u[2] = cvtpk(hi[0], hi[1]); af_.u[3] = cvtpk(hi[2], hi[3]);
      af[m] = af_.v;
    }
    bf16x8 bf0[4];
#pragma unroll
    for (int n = 0; n < 4; n++) {
      int row = wn*64 + n*16 + rA;
      bf0[n] = *(const bf16x8*)(bufc + 32768 + ((row*64 + g*16) ^ (((row >> 1) & 3) << 4)));
    }
    if (i < 14) PSTAGE(i + 2);
    __builtin_amdgcn_sched_barrier(0);
    __builtin_amdgcn_s_setprio(1);
#pragma unroll
    for (int m = 0; m < 4; m++)
#pragma unroll
      for (int n = 0; n < 4; n++)
        acc0[m][n] = __builtin_amdgcn_mfma_f32_16x16x32_bf16(af[m], bf0[n], acc0[m][n], 0, 0, 0);
    __builtin_amdgcn_s_setprio(0);
    if (DUAL) {
      bf16x8 bf1[4];
#pragma unroll
      for (int n = 0; n < 4; n++) {
        int row = wn*64 + n*16 + rA;
        bf1[n] = *(const bf16x8*)(bufc + 40960 + ((row*64 + g*16) ^ (((row >> 1) & 3) << 4)));
      }
      __builtin_amdgcn_s_setprio(1);
#pragma unroll
      for (int m = 0; m < 4; m++)
#pragma unroll
        for (int n = 0; n < 4; n++)
          acc1[m][n] = __builtin_amdgcn_mfma_f32_16x16x32_bf16(af[m], bf1[n], acc1[m][n], 0, 0, 0);
      __builtin_amdgcn_s_setprio(0);
    }
  }
#undef PSTAGE

#pragma unroll
  for (int m = 0; m < 4; m++)
#pragma unroll
    for (int n = 0; n < 4; n++) {
      int col = n0 + wn*64 + n*16 + rA;
      {
        float bb = bias0[col];
#pragma unroll
        for (int r = 0; r < 4; r++) {
          int row = m0 + wm*64 + m*16 + g*4 + r;
          out0[(size_t)row*512 + col] = f2b((acc0[m][n][r] + bb) * os);
        }
      }
      if (DUAL) {
        float bb = bias1[col];
        int b = m0 >> 9, k0 = m0 & 511;
        int hh = col >> 6, dl = col & 63;
        int kg = k0 + wm*64 + m*16 + g*4;
        float v0 = acc1[m][n][0] + bb, v1 = acc1[m][n][1] + bb;
        float v2 = acc1[m][n][2] + bb, v3 = acc1[m][n][3] + bb;
        uint2 pk;
        pk.x = (uint32_t)f2b(v0) | ((uint32_t)f2b(v1) << 16);
        pk.y = (uint32_t)f2b(v2) | ((uint32_t)f2b(v3) << 16);
        *(uint2*)(vpT + ((size_t)((b*8 + hh)*64 + dl)*512 + kg)) = pk;
      }
    }
}

// merged projection dispatch: z=0 -> Q-proj (scaled), z=1 -> fused K/V-proj.
__global__ __launch_bounds__(512, 1)
void k_proj(const float* __restrict__ Qf, const float* __restrict__ Kf,
            const ushort* __restrict__ Wb,
            const float* __restrict__ bq, const float* __restrict__ bk,
            const float* __restrict__ bvv,
            ushort* __restrict__ qp, ushort* __restrict__ kp, ushort* __restrict__ vpT)
{
  __shared__ __align__(16) char lds[3*49152];   // 144 KB (covers both bodies)
  if (blockIdx.z == 0) {
    proj_body<0>(Qf, Wb, nullptr, bq, nullptr, qp, nullptr,
                 lds, blockIdx.x*256, blockIdx.y*128, QSC_);
  } else {
    proj_body<1>(Kf, Wb + (size_t)262144, Wb + 2*(size_t)262144, bk, bvv, kp, vpT,
                 lds, blockIdx.x*256, blockIdx.y*128, 1.0f);
  }
}

// ---------------- fused attention: zinv (pass1, 16x16) + PV (pass2, 32x32 in-register P,
//                  software-pipelined fragment prefetch) ----------------
__global__ __launch_bounds__(512, 1)
void k_att2(const ushort* __restrict__ qp, const ushort* __restrict__ kp,
            const ushort* __restrict__ vpT, float* __restrict__ zinv,
            ushort* __restrict__ attn)
{
  __shared__ __align__(16) char kt[65536];
  __shared__ __align__(16) char vt[65536];
  __shared__ __align__(16) char qpr[32768];
  int bh = blockIdx.x;
  int b = bh >> 3, h = bh & 7;
  int t = threadIdx.x, w = t >> 6, lane = t & 63;
  int rA = lane & 15, g = lane >> 4;
  const ushort* kbase = kp + (size_t)(b*512)*512 + h*64;
  const ushort* qbase = qp + (size_t)(b*512)*512 + h*64;
  const ushort* vbase = vpT + (size_t)bh*64*512;

#pragma unroll
  for (int i = 0; i < 8; i++) {          // K: [512][64] swizzled slot^(k&7)
    int c = i*512 + t; int row = c >> 3, sl = c & 7;
    gld16(kt + c*16, kbase + (size_t)row*512 + ((sl ^ (row & 7))*8));
  }
#define STAGE_Q(buf, qb) do { \
    _Pragma("unroll") \
    for (int i = 0; i < 2; i++) { \
      int c = i*512 + t; int row = c >> 3, sl = c & 7; \
      gld16(qpr + (buf)*16384 + c*16, \
            qbase + (size_t)((qb)*128 + row)*512 + ((sl ^ (row & 7))*8)); } } while (0)
  STAGE_Q(0, 0);
  STAGE_Q(1, 1);
#pragma unroll
  for (int i = 0; i < 8; i++) {          // V: [64][512] swizzled slot low3 ^ (d&7)
    int c = i*512 + t; int d = c >> 6, sl = c & 63;
    gld16(vt + c*16, vbase + (size_t)d*512 + ((sl ^ (d & 7))*8));
  }

  // ---- pass 1: zl[k] = 1/sum_q 2^s; wave owns k in [w*64, w*64+64) ----
  asm volatile("s_waitcnt vmcnt(10)" ::: "memory");   // K + Q0 landed (Q1,V in flight)
  __builtin_amdgcn_s_barrier();
  __builtin_amdgcn_sched_barrier(0);
  bf16x8 kf[4][2];
#pragma unroll
  for (int n = 0; n < 4; n++)
#pragma unroll
    for (int ks = 0; ks < 2; ks++) {
      int k = w*64 + n*16 + rA;
      kf[n][ks] = *(const bf16x8*)(kt + k*128 + (((ks*4 + g) ^ (k & 7))*16));
    }
  float Zacc[4] = {0.f, 0.f, 0.f, 0.f};
  for (int qb = 0; qb < 4; qb++) {
    if (qb == 1)      { asm volatile("s_waitcnt vmcnt(10)" ::: "memory"); }
    else if (qb == 2) { asm volatile("s_waitcnt vmcnt(2)" ::: "memory"); }
    else if (qb == 3) { asm volatile("s_waitcnt vmcnt(0)" ::: "memory"); }
    if (qb) { __builtin_amdgcn_s_barrier(); __builtin_amdgcn_sched_barrier(0); }
    const char* qtb = qpr + (qb & 1)*16384;
    f32x4 acc[8][4] = {};
#pragma unroll
    for (int ks = 0; ks < 2; ks++) {
      bf16x8 af[8];
#pragma unroll
      for (int m = 0; m < 8; m++) {
        int q = m*16 + rA;
        af[m] = *(const bf16x8*)(qtb + q*128 + (((ks*4 + g) ^ (q & 7))*16));
      }
      __builtin_amdgcn_s_setprio(1);
#pragma unroll
      for (int m = 0; m < 8; m++)
#pragma unroll
        for (int n = 0; n < 4; n++)
          acc[m][n] = __builtin_amdgcn_mfma_f32_16x16x32_bf16(af[m], kf[n][ks], acc[m][n], 0, 0, 0);
      __builtin_amdgcn_s_setprio(0);
    }
    if (qb < 3) __builtin_amdgcn_s_barrier();
    if (qb < 2) STAGE_Q(qb & 1, qb + 2);
#pragma unroll
    for (int m = 0; m < 8; m++)
#pragma unroll
      for (int n = 0; n < 4; n++) {
        float s = 0.f;
#pragma unroll
        for (int r = 0; r < 4; r++) s += ex2(acc[m][n][r]);
        Zacc[n] += s;
      }
  }
#undef STAGE_Q
#pragma unroll
  for (int n = 0; n < 4; n++) {
    float v = Zacc[n];
    v += __shfl_xor(v, 16);
    v += __shfl_xor(v, 32);
    if (lane < 16) ((float*)qpr)[w*64 + n*16 + lane] = 1.0f / v;   // zl handoff in LDS
  }
  __syncthreads();

  // ---- pass 2: 32x32x16, P in registers; wave owns q in [w*64, w*64+64).
  //      Software-pipelined: fragments for kc+1 issued before kc's MFMA clusters. ----
  const int l31 = lane & 31, hi5 = lane >> 5;
  bf16x8 qf2[2][4];
#pragma unroll
  for (int qb = 0; qb < 2; qb++)
#pragma unroll
    for (int ksd = 0; ksd < 4; ksd++)
      qf2[qb][ksd] = *(const bf16x8*)(qbase + (size_t)(w*64 + qb*32 + l31)*512 + ksd*16 + hi5*8);
  const float* zl = (const float*)qpr;
  f32x16 oacc[2][2] = {};

#define LOADF(kc, KF, VF, ZV) do { \
    int k_ = (kc)*32 + l31; \
    _Pragma("unroll") \
    for (int ksd = 0; ksd < 4; ksd++) \
      KF[ksd] = *(const bf16x8*)(kt + k_*128 + (((ksd*2 + hi5) ^ (k_ & 7))*16)); \
    _Pragma("unroll") \
    for (int db = 0; db < 2; db++) \
      _Pragma("unroll") \
      for (int ks = 0; ks < 2; ks++) { \
        int d_ = db*32 + l31; \
        VF[db*2 + ks] = *(const bf16x8*)(vt + d_*1024 + ((((kc)*4 + ks*2 + hi5) ^ (d_ & 7))*16)); \
      } \
    _Pragma("unroll") \
    for (int j = 0; j < 4; j++) ZV[j] = *(const f32x4*)(zl + (kc)*32 + j*8 + hi5*4); \
  } while (0)

#define COMPUTE(KF, VF, ZV) do { \
    _Pragma("unroll") \
    for (int qb = 0; qb < 2; qb++) { \
      f32x16 s = {}; \
      __builtin_amdgcn_s_setprio(1); \
      _Pragma("unroll") \
      for (int ksd = 0; ksd < 4; ksd++) \
        s = __builtin_amdgcn_mfma_f32_32x32x16_bf16(KF[ksd], qf2[qb][ksd], s, 0, 0, 0); \
      __builtin_amdgcn_s_setprio(0); \
      float e[16]; \
      _Pragma("unroll") \
      for (int r = 0; r < 16; r++) e[r] = ex2(s[r]) * ZV[r >> 2][r & 3]; \
      uint32_t x0 = cvtpk(e[0], e[1]),   y0 = cvtpk(e[4], e[5]); \
      uint32_t x1 = cvtpk(e[2], e[3]),   y1 = cvtpk(e[6], e[7]); \
      uint32_t x2 = cvtpk(e[8], e[9]),   y2 = cvtpk(e[12], e[13]); \
      uint32_t x3 = cvtpk(e[10], e[11]), y3 = cvtpk(e[14], e[15]); \
      uint2v r0 = __builtin_amdgcn_permlane32_swap(x0, y0, false, false); \
      uint2v r1 = __builtin_amdgcn_permlane32_swap(x1, y1, false, false); \
      uint2v r2 = __builtin_amdgcn_permlane32_swap(x2, y2, false, false); \
      uint2v r3 = __builtin_amdgcn_permlane32_swap(x3, y3, false, false); \
      union { uint32_t u[4]; bf16x8 v; } p0, p1; \
      p0.u[0] = r0[0]; p0.u[1] = r1[0]; p0.u[2] = r0[1]; p0.u[3] = r1[1]; \
      p1.u[0] = r2[0]; p1.u[1] = r3[0]; p1.u[2] = r2[1]; p1.u[3] = r3[1]; \
      __builtin_amdgcn_s_setprio(1); \
      _Pragma("unroll") \
      for (int db = 0; db < 2; db++) { \
        oacc[qb][db] = __builtin_amdgcn_mfma_f32_32x32x16_bf16(p0.v, VF[db*2 + 0], oacc[qb][db], 0, 0, 0); \
        oacc[qb][db] = __builtin_amdgcn_mfma_f32_32x32x16_bf16(p1.v, VF[db*2 + 1], oacc[qb][db], 0, 0, 0); \
      } \
      __builtin_amdgcn_s_setprio(0); \
    } \
  } while (0)

  bf16x8 kfA[4], kfB[4], vfA[4], vfB[4];
  f32x4 zvA[4], zvB[4];
  LOADF(0, kfA, vfA, zvA);
  for (int kc2 = 0; kc2 < 8; kc2++) {
    LOADF(2*kc2 + 1, kfB, vfB, zvB);
    COMPUTE(kfA, vfA, zvA);
    if (kc2 < 7) LOADF(2*kc2 + 2, kfA, vfA, zvA);
    COMPUTE(kfB, vfB, zvB);
  }
#undef LOADF
#undef COMPUTE

#pragma unroll
  for (int qb = 0; qb < 2; qb++)
#pragma unroll
    for (int db = 0; db < 2; db++)
#pragma unroll
      for (int r = 0; r < 16; r++) {
        int q = w*64 + qb*32 + (r & 3) + 8*(r >> 2) + 4*hi5;
        int d = db*32 + l31;
        attn[(size_t)(b*512 + q)*512 + h*64 + d] = f2b(oacc[qb][db][r]);
      }
}

// ---------------- host launcher ----------------
extern "C" void kernel_launch(void* const* d_in, const int* in_sizes, int n_in,
                              void* d_out, int out_size, void* d_ws, size_t ws_size,
                              hipStream_t stream) {
  const float* Q  = (const float*)d_in[0];
  const float* K  = (const float*)d_in[1];
  const float* Wq = (const float*)d_in[2];
  const float* bq = (const float*)d_in[3];
  const float* Wk = (const float*)d_in[4];
  const float* bk = (const float*)d_in[5];
  const float* Wv = (const float*)d_in[6];
  const float* bv = (const float*)d_in[7];
  const float* Wo = (const float*)d_in[8];
  const float* bo = (const float*)d_in[9];
  const float* W1 = (const float*)d_in[10];
  const float* b1 = (const float*)d_in[11];
  const float* W2 = (const float*)d_in[12];
  const float* b2 = (const float*)d_in[13];
  float* out = (float*)d_out;

  const size_t SZ = (size_t)16384 * 512;
  ushort* attn = (ushort*)d_ws;                 // slot 0
  ushort* outb = attn + SZ;                     // slot 1
  ushort* qp   = outb + SZ;
  ushort* kp   = qp + SZ;
  ushort* vpT  = kp + SZ;                       // v-projection, transposed; later reused as h1
  ushort* Wb   = vpT + SZ;
  float*  zinv = (float*)(Wb + 6 * (size_t)262144);
  ushort* h1   = vpT;

  k_cvtw<<<dim3(1536), dim3(256), 0, stream>>>(Wq, Wk, Wv, Wo, W1, W2, Wb);
  k_proj<<<dim3(64, 4, 2), dim3(512), 0, stream>>>(Q, K, Wb, bq, bk, bv, qp, kp, vpT);
  k_att2<<<dim3(256), dim3(512), 0, stream>>>(qp, kp, vpT, zinv, attn);
  k_gemm<1><<<dim3(64, 4), dim3(512), 0, stream>>>(attn, Wb + 3*(size_t)262144, bo, Q, out, outb);
  k_gemm<2><<<dim3(64, 4), dim3(512), 0, stream>>>(outb, Wb + 4*(size_t)262144, b1, nullptr, nullptr, h1);
  k_gemm<3><<<dim3(64, 4), dim3(512), 0, stream>>>(h1, Wb + 5*(size_t)262144, b2, nullptr, out, nullptr);
}